// Round 3
// baseline (176.156 us; speedup 1.0000x reference)
//
#include <hip/hip_runtime.h>
#include <math.h>

// Problem: B=4, S=1024, F=256, H=8, FH=2048. SCALE=16 (multiplies logits).
#define SQ 1024
#define FQ 256
#define FH 2048

typedef _Float16 f16;
typedef f16  f16x8 __attribute__((ext_vector_type(8)));
typedef f16  f16x4 __attribute__((ext_vector_type(4)));
typedef float f32x4 __attribute__((ext_vector_type(4)));

// Async global->LDS, 16 B/lane. LDS dest = wave-uniform base + lane*16.
// Side-effecting intrinsic: cannot be sunk past barriers by the compiler.
#define GLOAD_LDS16(gp, lp) \
    __builtin_amdgcn_global_load_lds((const __attribute__((address_space(1))) void*)(gp), \
                                     (__attribute__((address_space(3))) void*)(lp), 16, 0, 0)

// sigmoid(16*s) = rcp(1+exp2(-16*log2(e)*s)); v_rcp+v_exp, no IEEE divide.
#define SIG16(s) __builtin_amdgcn_rcpf(1.0f + __builtin_amdgcn_exp2f(-23.083120654223414f * (s)))

// ---------------------------------------------------------------------------
// prep kernel: z=0..2 transpose Wq/Wk/Wv (256x2048 fp32 -> 2048x256 f16);
// z=3 transpose Wo with k permuted to h*256+f; z=4 cvt x fp32->f16.
// ---------------------------------------------------------------------------
__global__ __launch_bounds__(256) void prep_kernel(const float* __restrict__ x,
                                                   const float* __restrict__ Wq,
                                                   const float* __restrict__ Wk,
                                                   const float* __restrict__ Wv,
                                                   const float* __restrict__ Wo,
                                                   f16* __restrict__ xh,
                                                   f16* __restrict__ wqT,
                                                   f16* __restrict__ wkT,
                                                   f16* __restrict__ wvT,
                                                   f16* __restrict__ woT) {
    const int z = blockIdx.z;
    if (z == 4) {
        int id = (int)(blockIdx.x * 8 + blockIdx.y);
        int idx = (id * 256 + (int)threadIdx.x) * 8;
        float4 a = *(const float4*)(x + idx);
        float4 b = *(const float4*)(x + idx + 4);
        f16x8 v = {(f16)a.x, (f16)a.y, (f16)a.z, (f16)a.w,
                   (f16)b.x, (f16)b.y, (f16)b.z, (f16)b.w};
        *(f16x8*)(xh + idx) = v;
        return;
    }
    __shared__ f16 T[32][33];
    const int tx = threadIdx.x & 31, ty = threadIdx.x >> 5;
    if (z < 3) {
        const float* W = z == 0 ? Wq : (z == 1 ? Wk : Wv);
        f16* WT        = z == 0 ? wqT : (z == 1 ? wkT : wvT);
        const int n0 = blockIdx.x * 32, k0 = blockIdx.y * 32;
#pragma unroll
        for (int i = 0; i < 4; ++i)
            T[ty + i * 8][tx] = (f16)W[(size_t)(k0 + ty + i * 8) * FH + n0 + tx];
        __syncthreads();
#pragma unroll
        for (int i = 0; i < 4; ++i)
            WT[(size_t)(n0 + ty + i * 8) * FQ + k0 + tx] = T[tx][ty + i * 8];
    } else {
        const int n0 = (blockIdx.x >> 3) * 32;
        const int yy = (blockIdx.x & 7) * 8 + blockIdx.y;   // 0..63
        const int ft = yy >> 3, h = yy & 7;
#pragma unroll
        for (int i = 0; i < 4; ++i) {
            int fl = ty + i * 8;
            T[fl][tx] = (f16)Wo[(size_t)((ft * 32 + fl) * 8 + h) * FQ + n0 + tx];
        }
        __syncthreads();
#pragma unroll
        for (int i = 0; i < 4; ++i)
            woT[(size_t)(n0 + ty + i * 8) * FH + h * 256 + ft * 32 + tx] = T[tx][ty + i * 8];
    }
}

// ---------------------------------------------------------------------------
// Swizzled staging, LDS row stride 64 f16 (BK=64 GEMM tiles).
// ---------------------------------------------------------------------------
__device__ __forceinline__ void stage_sw64(const f16* __restrict__ G, int ldg,
                                           int row0, int c0, f16* S,
                                           int nrows, int w, int lane) {
    const int rsub = lane >> 3;           // 0..7
    const int g    = (lane & 7) ^ (rsub & 7);
#pragma unroll
    for (int rI = w; rI < (nrows >> 3); rI += 4) {
        GLOAD_LDS16(G + (size_t)(row0 + rI * 8 + rsub) * ldg + c0 + g * 8,
                    S + rI * 512);
    }
}

// ---------------------------------------------------------------------------
// 128x128 MFMA tile, BK=64 swizzled staging. 4 waves 2x2 of 64x64.
// ---------------------------------------------------------------------------
__device__ __forceinline__ void gemm128_sw(const f16* __restrict__ A, int lda,
                                           const f16* __restrict__ Bt, int ldb,
                                           int kbeg, int kend, f16* As, f16* Bs,
                                           f32x4 acc[4][4], int row0, int col0) {
    const int t = threadIdx.x, lane = t & 63, w = t >> 6;
    const int wr = w >> 1, wc = w & 1;
    const int lrow = lane & 15, quad = lane >> 4;
    for (int k0 = kbeg; k0 < kend; k0 += 64) {
        __syncthreads();
        stage_sw64(A, lda, row0, k0, As, 128, w, lane);
        stage_sw64(Bt, ldb, col0, k0, Bs, 128, w, lane);
        __syncthreads();
#pragma unroll
        for (int kk = 0; kk < 2; ++kk) {
            f16x8 af[4], bf[4];
#pragma unroll
            for (int i = 0; i < 4; ++i) {
                int r = wr * 64 + i * 16 + lrow;
                af[i] = *(const f16x8*)&As[r * 64 + (((kk * 4 + quad) ^ (r & 7)) << 3)];
            }
#pragma unroll
            for (int j = 0; j < 4; ++j) {
                int r = wc * 64 + j * 16 + lrow;
                bf[j] = *(const f16x8*)&Bs[r * 64 + (((kk * 4 + quad) ^ (r & 7)) << 3)];
            }
#pragma unroll
            for (int i = 0; i < 4; ++i)
#pragma unroll
                for (int j = 0; j < 4; ++j)
                    acc[i][j] = __builtin_amdgcn_mfma_f32_16x16x32_f16(af[i], bf[j], acc[i][j], 0, 0, 0);
        }
    }
}

// ---------------------------------------------------------------------------
// Merged QKV projection with coalesced LDS-roundtrip epilogue.
// z=0 Q -> (b,h,s,f); z=1 K -> (b,h,s,f); z=2 V -> (b,h,f,s).
// ---------------------------------------------------------------------------
__global__ __launch_bounds__(256) void proj_mfma(const f16* __restrict__ xh,
                                                 const f16* __restrict__ wqT,
                                                 const f16* __restrict__ wkT,
                                                 const f16* __restrict__ wvT,
                                                 f16* __restrict__ qb,
                                                 f16* __restrict__ kb,
                                                 f16* __restrict__ vb) {
    const int z = blockIdx.z;
    const f16* WT = z == 0 ? wqT : (z == 1 ? wkT : wvT);
    f16* O        = z == 0 ? qb  : (z == 1 ? kb  : vb);
    __shared__ f16 smem[17408];          // As|Bs (16384) ; Es (17408) alias
    f16* As = smem;
    f16* Bs = smem + 8192;
    f32x4 acc[4][4] = {};
    const int row0 = blockIdx.y * 128, col0 = blockIdx.x * 128;
    gemm128_sw(xh, FQ, WT, FQ, 0, FQ, As, Bs, acc, row0, col0);

    __syncthreads();                     // As/Bs dead -> reuse as Es
    f16* Es = smem;                      // ld 136
    const int lane = threadIdx.x & 63, w = threadIdx.x >> 6;
    const int wr = w >> 1, wc = w & 1;
    const int lrow = lane & 15, quad = lane >> 4;
    if (z != 2) {
#pragma unroll
        for (int i = 0; i < 4; ++i)
#pragma unroll
            for (int rr = 0; rr < 4; ++rr) {
                int rl = 64 * wr + 16 * i + 4 * quad + rr;
#pragma unroll
                for (int j = 0; j < 4; ++j) {
                    int cc = 64 * wc + 16 * j + lrow;
                    Es[rl * 136 + (cc & 7) * 16 + (cc >> 3)] = (f16)acc[i][j][rr];
                }
            }
        __syncthreads();
        const int f0 = col0 >> 3;
#pragma unroll
        for (int it = 0; it < 4; ++it) {
            int c = it * 256 + threadIdx.x;
            int row = c >> 3, hh = c & 7;
            int gr = row0 + row, bbb = gr >> 10, s = gr & 1023;
            f16x8 v0 = *(const f16x8*)&Es[row * 136 + hh * 16];
            f16x8 v1 = *(const f16x8*)&Es[row * 136 + hh * 16 + 8];
            f16* dst = O + ((size_t)(bbb * 8 + hh) * SQ + s) * FQ + f0;
            *(f16x8*)dst = v0;
            *(f16x8*)(dst + 8) = v1;
        }
    } else {
#pragma unroll
        for (int i = 0; i < 4; ++i)
#pragma unroll
            for (int rr = 0; rr < 4; ++rr) {
                int rl = 64 * wr + 16 * i + 4 * quad + rr;
#pragma unroll
                for (int j = 0; j < 4; ++j) {
                    int cc = 64 * wc + 16 * j + lrow;
                    Es[cc * 136 + rl] = (f16)acc[i][j][rr];
                }
            }
        __syncthreads();
        const int bbb = row0 >> 10, s0 = row0 & 1023;
#pragma unroll
        for (int it = 0; it < 8; ++it) {
            int c = it * 256 + threadIdx.x;
            int cc = c >> 4, sc = c & 15;
            int hh = cc & 7, f = (col0 >> 3) + (cc >> 3);
            f16x8 v = *(const f16x8*)&Es[cc * 136 + sc * 8];
            *(f16x8*)(O + ((size_t)(bbb * 8 + hh) * FQ + f) * SQ + s0 + sc * 8) = v;
        }
    }
}

// ---------------------------------------------------------------------------
// Fused attention v11 — swapped QK^T + in-register P (no LDS roundtrip).
// 8 waves (512 threads), M=32/wave, in-block split-j (grp0 even j-tiles,
// grp1 odd), as v10b. NEW vs v10b:
//  * QK computed SWAPPED: mfma(K-frag, Q-frag) -> S^T tile. D-layout puts
//    q in lanes (col=lane&15) and j in regs (row=4*quad+rr): each lane
//    holds, for its own q-row, j = 16nj+4quad+rr -- 8 j-values in-lane.
//  * PV uses mfma_f32_16x16x16f16 (K=16): A-frag wants A[q][k=4quad+e] =
//    P[q][16nj+4quad+e] -- exactly the lane's sigmoid outputs (e=rr).
//    P transpose through LDS ELIMINATED (was 16 b16 writes + 2 b128 reads
//    + lgkmcnt latency on the serial path every iteration).
//  * V read as ds_read_b64 of 4 contiguous j at [f][16nj+4quad]; staging
//    swizzle unchanged (16B granule p = g ^ ((f>>1)&3)); bank-balanced.
// Rationale (rocprof v10b): occupancy doubled but MfmaUtil only 24%,
// VALU+MFMA < 50% -> serial per-iter chain + LDS pipe. This cuts LDS
// ops/wave-iter ~23% and removes the P write->read latency link.
// LDS: K 4x16KB + V 4x16KB = 128 KB in a 151552-B array (epilogue Es/Fb
// regions unchanged).
// ---------------------------------------------------------------------------
__global__ __launch_bounds__(512, 2) void fused_attn(const f16* __restrict__ Qb,
                                                     const f16* __restrict__ Kb,
                                                     const f16* __restrict__ Vt,
                                                     f16* __restrict__ WV) {
    __shared__ f16 smem[75776];   // K slots 4x8192 | V slots 4x8192 | epilogue scratch
    const int t = threadIdx.x, lane = t & 63, w = t >> 6;   // w 0..7
    const int grp = w >> 2, wl = w & 3;
    const int lrow = lane & 15, quad = lane >> 4;
    // XCD swizzle: 4 consecutive heads per XCD -> Q/K/V L2-resident per XCD.
    const int n = blockIdx.x;                    // 0..255
    const int xcd = n & 7, rest = n >> 3;        // rest 0..31
    const int bh = xcd * 4 + (rest & 3);
    const int strip = rest >> 2;                 // 0..7
    const int m0 = strip * 128;
    const int bb = bh >> 3, h = bh & 7;
    const f16* Qg = Qb + (size_t)bh * SQ * FQ;   // (s,f)
    const f16* Kg = Kb + (size_t)bh * SQ * FQ;   // (s,f)
    const f16* Vg = Vt + (size_t)bh * FQ * SQ;   // (f,s)

    // Q rows [m0+32*wl, +32) as MFMA fragments in registers (64 VGPR).
    // Used as the B-operand of the swapped QK (frag lane-map identical).
    f16x8 qf[2][8];
#pragma unroll
    for (int mi = 0; mi < 2; ++mi)
#pragma unroll
        for (int ks = 0; ks < 8; ++ks)
            qf[mi][ks] = *(const f16x8*)(Qg + (size_t)(m0 + 32 * wl + 16 * mi + lrow) * FQ
                                             + ks * 32 + quad * 8);

    // K staging geometry: per tile 16 insts, 2 rows x 32 granules each.
    // KB[r][p] holds source granule p^(r&7); read logical g at p = g^(r&7).
    const int krs = lane >> 5;                   // 0..1
    const int kgp = lane & 31;
    // V staging geometry: per tile 16 insts, 16 rows x 4 granules each.
    // VB[f][p] holds source granule p^((f>>1)&3); read at p = g^((f>>1)&3).
    const int vrs = lane >> 2;                   // 0..15
    const int vgp = lane & 3;

    // Prologue: stage tiles {0,1} of K and V into parity-0 slots.
    // grp0 waves stage K (2 tiles x 4 insts), grp1 waves stage V.
    if (grp == 0) {
#pragma unroll
        for (int kt = 0; kt < 2; ++kt)
#pragma unroll
            for (int i = 0; i < 4; ++i) {
                int rI = wl + i * 4;
                int r = rI * 2 + krs;
                GLOAD_LDS16(Kg + (size_t)(kt * 32 + r) * FQ + ((kgp ^ (r & 7)) << 3),
                            smem + kt * 8192 + rI * 512);
            }
    } else {
#pragma unroll
        for (int kt = 0; kt < 2; ++kt)
#pragma unroll
            for (int i = 0; i < 4; ++i) {
                int rI = wl + i * 4;
                int f = rI * 16 + vrs;
                GLOAD_LDS16(Vg + (size_t)f * SQ + kt * 32 + ((vgp ^ ((f >> 1) & 3)) << 3),
                            smem + 32768 + kt * 8192 + rI * 512);
            }
    }

    f32x4 acc_o[2][16] = {};   // rows m0+32wl+16mi+4quad+rr, f = 16nj+lrow

    for (int it = 0; it < 16; ++it) {
        const int p = it & 1;
        f16* KBc = smem + (p * 2 + grp) * 8192;
        f16* VBc = smem + 32768 + (p * 2 + grp) * 8192;
        __syncthreads();                 // drains tiles for iter it (issued it-1)
        // ---- issue K/V tiles {2(it+1), 2(it+1)+1} into the other parity ----
        if (it < 15) {
            const int pn = p ^ 1;
            const int base = (it + 1) * 64;
            if (grp == 0) {
#pragma unroll
                for (int kt = 0; kt < 2; ++kt)
#pragma unroll
                    for (int i = 0; i < 4; ++i) {
                        int rI = wl + i * 4;
                        int r = rI * 2 + krs;
                        GLOAD_LDS16(Kg + (size_t)(base + kt * 32 + r) * FQ + ((kgp ^ (r & 7)) << 3),
                                    smem + (pn * 2 + kt) * 8192 + rI * 512);
                    }
            } else {
#pragma unroll
                for (int kt = 0; kt < 2; ++kt)
#pragma unroll
                    for (int i = 0; i < 4; ++i) {
                        int rI = wl + i * 4;
                        int f = rI * 16 + vrs;
                        GLOAD_LDS16(Vg + (size_t)f * SQ + base + kt * 32 + ((vgp ^ ((f >> 1) & 3)) << 3),
                                    smem + 32768 + (pn * 2 + kt) * 8192 + rI * 512);
                    }
            }
        }
        // ---- QK^T SWAPPED: acc_s[nj][mi] = S^T; j = 16nj+4quad+rr, q = 16mi+lrow ----
        f32x4 acc_s[2][2] = {};
#pragma unroll
        for (int ks = 0; ks < 8; ++ks) {
            f16x8 bf[2];
#pragma unroll
            for (int nj = 0; nj < 2; ++nj) {
                int rk = 16 * nj + lrow;
                bf[nj] = *(const f16x8*)&KBc[rk * 256 + (((ks * 4 + quad) ^ (rk & 7)) << 3)];
            }
#pragma unroll
            for (int nj = 0; nj < 2; ++nj)
#pragma unroll
                for (int mi = 0; mi < 2; ++mi)
                    acc_s[nj][mi] = __builtin_amdgcn_mfma_f32_16x16x32_f16(
                        bf[nj], qf[mi][ks], acc_s[nj][mi], 0, 0, 0);
        }
        // ---- sigmoid + pack: P A-fragments built fully in-register ----
        f16x4 ap[2][2];
#pragma unroll
        for (int nj = 0; nj < 2; ++nj)
#pragma unroll
            for (int mi = 0; mi < 2; ++mi) {
                f16x4 v;
#pragma unroll
                for (int rr = 0; rr < 4; ++rr)
                    v[rr] = (f16)SIG16(acc_s[nj][mi][rr]);
                ap[nj][mi] = v;
            }
        // ---- PV via 16x16x16 MFMA: k-half nj; A = ap (in-lane), B = V b64 reads ----
        __builtin_amdgcn_s_setprio(1);
#pragma unroll
        for (int njf = 0; njf < 16; ++njf) {
            const int f = 16 * njf + lrow;
            const int sw = (f >> 1) & 3;
#pragma unroll
            for (int nj = 0; nj < 2; ++nj) {
                const int g16 = 2 * nj + (quad >> 1);
                f16x4 bv = *(const f16x4*)&VBc[f * 32 + ((g16 ^ sw) << 3) + ((quad & 1) << 2)];
#pragma unroll
                for (int mi = 0; mi < 2; ++mi)
                    acc_o[mi][njf] = __builtin_amdgcn_mfma_f32_16x16x16f16(
                        ap[nj][mi], bv, acc_o[mi][njf], 0, 0, 0);
            }
        }
        __builtin_amdgcn_s_setprio(0);
    }
    // ---- combine the two j-half partials (f32, exact), TWO passes over mi ----
    // Per pass: Fb = 64 chunks x 256 f32 = 64 KB at byte 69632 (in-bounds:
    // ends 135168 <= 151552); Es f16 [0, 67584) -- disjoint.
    __syncthreads();                             // all compute reads of smem done
    float* Fb = (float*)(smem + 34816);
    f16* Es = smem;                              // 128 x 264 f16
#pragma unroll
    for (int mi = 0; mi < 2; ++mi) {
        if (grp == 1) {
#pragma unroll
            for (int nj = 0; nj < 16; ++nj)
                *(f32x4*)&Fb[((wl * 16 + nj) << 8) + lane * 4] = acc_o[mi][nj];
        }
        __syncthreads();
        if (grp == 0) {
#pragma unroll
            for (int nj = 0; nj < 16; ++nj) {
                f32x4 s = acc_o[mi][nj] +
                          *(const f32x4*)&Fb[((wl * 16 + nj) << 8) + lane * 4];
#pragma unroll
                for (int rr = 0; rr < 4; ++rr)
                    Es[(32 * wl + 16 * mi + 4 * quad + rr) * 264 + 16 * nj + lrow] =
                        (f16)s[rr];
            }
        }
        __syncthreads();                 // Fb reads done before mi=1 overwrite;
    }                                    // also orders Es for the global write
#pragma unroll
    for (int it = 0; it < 8; ++it) {
        int c = it * 512 + t;
        int r = c >> 5, ck = c & 31;
        f16x8 v = *(const f16x8*)&Es[r * 264 + ck * 8];
        *(f16x8*)(WV + (size_t)(bb * SQ + m0 + r) * FH + h * 256 + ck * 8) = v;
    }
}

// ---------------------------------------------------------------------------
// out projection, split-K x8 over k = h*256+f. 128x128 tiles, grid (2,32,8).
// fp32 partials ALIASED onto dead qbuf/kbuf workspace (32 MB) -- no OOB.
// ---------------------------------------------------------------------------
__global__ __launch_bounds__(256) void out_mfma8(const f16* __restrict__ WVm,
                                                 const f16* __restrict__ WoT,
                                                 float* __restrict__ PP) {
    __shared__ f16 smem[16384];
    f16* As = smem;
    f16* Bs = smem + 8192;
    f32x4 acc[4][4] = {};
    const int row0 = blockIdx.y * 128, col0 = blockIdx.x * 128;
    const int kbeg = blockIdx.z * 256;
    gemm128_sw(WVm, FH, WoT, FH, kbeg, kbeg + 256, As, Bs, acc, row0, col0);

    float* P = PP + (size_t)blockIdx.z * SQ * 4 * FQ;
    const int lane = threadIdx.x & 63, w = threadIdx.x >> 6;
    const int wr = w >> 1, wc = w & 1;
    const int lrow = lane & 15, quad = lane >> 4;
#pragma unroll
    for (int i = 0; i < 4; ++i)
#pragma unroll
        for (int rr = 0; rr < 4; ++rr) {
            int gr = row0 + wr * 64 + i * 16 + quad * 4 + rr;
#pragma unroll
            for (int j = 0; j < 4; ++j) {
                int gc = col0 + wc * 64 + j * 16 + lrow;
                P[(size_t)gr * FQ + gc] = acc[i][j][rr];
            }
        }
}

__global__ __launch_bounds__(256) void reduce_relu8(const float* __restrict__ PP,
                                                    float* __restrict__ O) {
    int idx = (blockIdx.x * 256 + threadIdx.x) * 4;
    f32x4 s = *(const f32x4*)(PP + idx);
#pragma unroll
    for (int z = 1; z < 8; ++z)
        s += *(const f32x4*)(PP + (size_t)z * 1048576 + idx);
    f32x4 r = {fmaxf(s.x, 0.f), fmaxf(s.y, 0.f), fmaxf(s.z, 0.f), fmaxf(s.w, 0.f)};
    *(f32x4*)(O + idx) = r;
}

// ---------------------------------------------------------------------------
extern "C" void kernel_launch(void* const* d_in, const int* in_sizes, int n_in,
                              void* d_out, int out_size, void* d_ws, size_t ws_size,
                              hipStream_t stream) {
    const float* x  = (const float*)d_in[0];
    const float* Wq = (const float*)d_in[1];
    const float* Wk = (const float*)d_in[2];
    const float* Wv = (const float*)d_in[3];
    const float* Wo = (const float*)d_in[4];
    float* out = (float*)d_out;

    f16* ws = (f16*)d_ws;
    f16* xh    = ws;                       // 1,048,576
    f16* wqT   = xh    + 1048576;          // 524,288
    f16* wkT   = wqT   + 524288;
    f16* wvT   = wkT   + 524288;
    f16* woT   = wvT   + 524288;           // 524,288 (k permuted to h*256+f)
    f16* qbuf  = woT   + 524288;           // 8,388,608 (b,h,s,f)
    f16* kbuf  = qbuf  + 8388608;          // (b,h,s,f)
    f16* vbuf  = kbuf  + 8388608;          // (b,h,f,s)
    f16* wvbuf = vbuf  + 8388608;          // (b*s, h*256+f)
    // pp ALIASES qbuf+kbuf (dead after fused_attn): 8 x 1,048,576 fp32 = 32 MB.
    float* pp  = (float*)qbuf;

    dim3 blk(256);
    prep_kernel<<<dim3(64, 8, 5), blk, 0, stream>>>(x, Wq, Wk, Wv, Wo,
                                                    xh, wqT, wkT, wvT, woT);

    proj_mfma<<<dim3(16, 32, 3), blk, 0, stream>>>(xh, wqT, wkT, wvT, qbuf, kbuf, vbuf);

    fused_attn<<<dim3(256), dim3(512), 0, stream>>>(qbuf, kbuf, vbuf, wvbuf);

    out_mfma8<<<dim3(2, 32, 8), blk, 0, stream>>>(wvbuf, woT, pp);
    reduce_relu8<<<dim3(1024), blk, 0, stream>>>(pp, out);
}

// Round 4
// 160.617 us; speedup vs baseline: 1.0967x; 1.0967x over previous
//
#include <hip/hip_runtime.h>
#include <math.h>

// Problem: B=4, S=1024, F=256, H=8, FH=2048. SCALE=16 (multiplies logits).
#define SQ 1024
#define FQ 256
#define FH 2048

typedef _Float16 f16;
typedef f16  f16x8 __attribute__((ext_vector_type(8)));
typedef f16  f16x4 __attribute__((ext_vector_type(4)));
typedef float f32x4 __attribute__((ext_vector_type(4)));

// Async global->LDS, 16 B/lane. LDS dest = wave-uniform base + lane*16.
// Side-effecting intrinsic: cannot be sunk past barriers by the compiler.
#define GLOAD_LDS16(gp, lp) \
    __builtin_amdgcn_global_load_lds((const __attribute__((address_space(1))) void*)(gp), \
                                     (__attribute__((address_space(3))) void*)(lp), 16, 0, 0)

// sigmoid(16*s) = rcp(1+exp2(-16*log2(e)*s)); v_rcp+v_exp, no IEEE divide.
#define SIG16(s) __builtin_amdgcn_rcpf(1.0f + __builtin_amdgcn_exp2f(-23.083120654223414f * (s)))

// ---------------------------------------------------------------------------
// prep kernel: z=0..2 transpose Wq/Wk/Wv (256x2048 fp32 -> 2048x256 f16);
// z=3 transpose Wo with k permuted to h*256+f; z=4 cvt x fp32->f16.
// ---------------------------------------------------------------------------
__global__ __launch_bounds__(256) void prep_kernel(const float* __restrict__ x,
                                                   const float* __restrict__ Wq,
                                                   const float* __restrict__ Wk,
                                                   const float* __restrict__ Wv,
                                                   const float* __restrict__ Wo,
                                                   f16* __restrict__ xh,
                                                   f16* __restrict__ wqT,
                                                   f16* __restrict__ wkT,
                                                   f16* __restrict__ wvT,
                                                   f16* __restrict__ woT) {
    const int z = blockIdx.z;
    if (z == 4) {
        int id = (int)(blockIdx.x * 8 + blockIdx.y);
        int idx = (id * 256 + (int)threadIdx.x) * 8;
        float4 a = *(const float4*)(x + idx);
        float4 b = *(const float4*)(x + idx + 4);
        f16x8 v = {(f16)a.x, (f16)a.y, (f16)a.z, (f16)a.w,
                   (f16)b.x, (f16)b.y, (f16)b.z, (f16)b.w};
        *(f16x8*)(xh + idx) = v;
        return;
    }
    __shared__ f16 T[32][33];
    const int tx = threadIdx.x & 31, ty = threadIdx.x >> 5;
    if (z < 3) {
        const float* W = z == 0 ? Wq : (z == 1 ? Wk : Wv);
        f16* WT        = z == 0 ? wqT : (z == 1 ? wkT : wvT);
        const int n0 = blockIdx.x * 32, k0 = blockIdx.y * 32;
#pragma unroll
        for (int i = 0; i < 4; ++i)
            T[ty + i * 8][tx] = (f16)W[(size_t)(k0 + ty + i * 8) * FH + n0 + tx];
        __syncthreads();
#pragma unroll
        for (int i = 0; i < 4; ++i)
            WT[(size_t)(n0 + ty + i * 8) * FQ + k0 + tx] = T[tx][ty + i * 8];
    } else {
        const int n0 = (blockIdx.x >> 3) * 32;
        const int yy = (blockIdx.x & 7) * 8 + blockIdx.y;   // 0..63
        const int ft = yy >> 3, h = yy & 7;
#pragma unroll
        for (int i = 0; i < 4; ++i) {
            int fl = ty + i * 8;
            T[fl][tx] = (f16)Wo[(size_t)((ft * 32 + fl) * 8 + h) * FQ + n0 + tx];
        }
        __syncthreads();
#pragma unroll
        for (int i = 0; i < 4; ++i)
            woT[(size_t)(n0 + ty + i * 8) * FH + h * 256 + ft * 32 + tx] = T[tx][ty + i * 8];
    }
}

// ---------------------------------------------------------------------------
// Swizzled staging, LDS row stride 64 f16 (BK=64 GEMM tiles).
// ---------------------------------------------------------------------------
__device__ __forceinline__ void stage_sw64(const f16* __restrict__ G, int ldg,
                                           int row0, int c0, f16* S,
                                           int nrows, int w, int lane) {
    const int rsub = lane >> 3;           // 0..7
    const int g    = (lane & 7) ^ (rsub & 7);
#pragma unroll
    for (int rI = w; rI < (nrows >> 3); rI += 4) {
        GLOAD_LDS16(G + (size_t)(row0 + rI * 8 + rsub) * ldg + c0 + g * 8,
                    S + rI * 512);
    }
}

// ---------------------------------------------------------------------------
// 128x128 MFMA tile, BK=64 swizzled staging. 4 waves 2x2 of 64x64.
// ---------------------------------------------------------------------------
__device__ __forceinline__ void gemm128_sw(const f16* __restrict__ A, int lda,
                                           const f16* __restrict__ Bt, int ldb,
                                           int kbeg, int kend, f16* As, f16* Bs,
                                           f32x4 acc[4][4], int row0, int col0) {
    const int t = threadIdx.x, lane = t & 63, w = t >> 6;
    const int wr = w >> 1, wc = w & 1;
    const int lrow = lane & 15, quad = lane >> 4;
    for (int k0 = kbeg; k0 < kend; k0 += 64) {
        __syncthreads();
        stage_sw64(A, lda, row0, k0, As, 128, w, lane);
        stage_sw64(Bt, ldb, col0, k0, Bs, 128, w, lane);
        __syncthreads();
#pragma unroll
        for (int kk = 0; kk < 2; ++kk) {
            f16x8 af[4], bf[4];
#pragma unroll
            for (int i = 0; i < 4; ++i) {
                int r = wr * 64 + i * 16 + lrow;
                af[i] = *(const f16x8*)&As[r * 64 + (((kk * 4 + quad) ^ (r & 7)) << 3)];
            }
#pragma unroll
            for (int j = 0; j < 4; ++j) {
                int r = wc * 64 + j * 16 + lrow;
                bf[j] = *(const f16x8*)&Bs[r * 64 + (((kk * 4 + quad) ^ (r & 7)) << 3)];
            }
#pragma unroll
            for (int i = 0; i < 4; ++i)
#pragma unroll
                for (int j = 0; j < 4; ++j)
                    acc[i][j] = __builtin_amdgcn_mfma_f32_16x16x32_f16(af[i], bf[j], acc[i][j], 0, 0, 0);
        }
    }
}

// ---------------------------------------------------------------------------
// Merged QKV projection with coalesced LDS-roundtrip epilogue.
// z=0 Q -> (b,h,s,f); z=1 K -> (b,h,s,f); z=2 V -> (b,h,f,s).
// ---------------------------------------------------------------------------
__global__ __launch_bounds__(256) void proj_mfma(const f16* __restrict__ xh,
                                                 const f16* __restrict__ wqT,
                                                 const f16* __restrict__ wkT,
                                                 const f16* __restrict__ wvT,
                                                 f16* __restrict__ qb,
                                                 f16* __restrict__ kb,
                                                 f16* __restrict__ vb) {
    const int z = blockIdx.z;
    const f16* WT = z == 0 ? wqT : (z == 1 ? wkT : wvT);
    f16* O        = z == 0 ? qb  : (z == 1 ? kb  : vb);
    __shared__ f16 smem[17408];          // As|Bs (16384) ; Es (17408) alias
    f16* As = smem;
    f16* Bs = smem + 8192;
    f32x4 acc[4][4] = {};
    const int row0 = blockIdx.y * 128, col0 = blockIdx.x * 128;
    gemm128_sw(xh, FQ, WT, FQ, 0, FQ, As, Bs, acc, row0, col0);

    __syncthreads();                     // As/Bs dead -> reuse as Es
    f16* Es = smem;                      // ld 136
    const int lane = threadIdx.x & 63, w = threadIdx.x >> 6;
    const int wr = w >> 1, wc = w & 1;
    const int lrow = lane & 15, quad = lane >> 4;
    if (z != 2) {
#pragma unroll
        for (int i = 0; i < 4; ++i)
#pragma unroll
            for (int rr = 0; rr < 4; ++rr) {
                int rl = 64 * wr + 16 * i + 4 * quad + rr;
#pragma unroll
                for (int j = 0; j < 4; ++j) {
                    int cc = 64 * wc + 16 * j + lrow;
                    Es[rl * 136 + (cc & 7) * 16 + (cc >> 3)] = (f16)acc[i][j][rr];
                }
            }
        __syncthreads();
        const int f0 = col0 >> 3;
#pragma unroll
        for (int it = 0; it < 4; ++it) {
            int c = it * 256 + threadIdx.x;
            int row = c >> 3, hh = c & 7;
            int gr = row0 + row, bbb = gr >> 10, s = gr & 1023;
            f16x8 v0 = *(const f16x8*)&Es[row * 136 + hh * 16];
            f16x8 v1 = *(const f16x8*)&Es[row * 136 + hh * 16 + 8];
            f16* dst = O + ((size_t)(bbb * 8 + hh) * SQ + s) * FQ + f0;
            *(f16x8*)dst = v0;
            *(f16x8*)(dst + 8) = v1;
        }
    } else {
#pragma unroll
        for (int i = 0; i < 4; ++i)
#pragma unroll
            for (int rr = 0; rr < 4; ++rr) {
                int rl = 64 * wr + 16 * i + 4 * quad + rr;
#pragma unroll
                for (int j = 0; j < 4; ++j) {
                    int cc = 64 * wc + 16 * j + lrow;
                    Es[cc * 136 + rl] = (f16)acc[i][j][rr];
                }
            }
        __syncthreads();
        const int bbb = row0 >> 10, s0 = row0 & 1023;
#pragma unroll
        for (int it = 0; it < 8; ++it) {
            int c = it * 256 + threadIdx.x;
            int cc = c >> 4, sc = c & 15;
            int hh = cc & 7, f = (col0 >> 3) + (cc >> 3);
            f16x8 v = *(const f16x8*)&Es[cc * 136 + sc * 8];
            *(f16x8*)(O + ((size_t)(bbb * 8 + hh) * FQ + f) * SQ + s0 + sc * 8) = v;
        }
    }
}

// ---------------------------------------------------------------------------
// Fused attention v12 — swapped QK^T + VECTORIZED P round-trip + x32 PV.
// 8 waves (512 threads), M=32/wave, in-block split-j (grp0 even j-tiles,
// grp1 odd), as v10b/v11.
// Post-mortem v11: x16 PV MFMA is rate-inferior (2x instr at same issue
// slot) and V b64 reads 4-way bank-conflict (2.36M -> 6.29M cycles). v12
// keeps v11's swapped QK (lane holds its own q-row's P, j-contiguous) but
// restores v10b's x32 PV + b128 V reads (measured-fine), and writes P to
// the wave-private Pw buffer as 4x ds_write_b64 per iter instead of
// v10b's 16x ds_write_b16 (write banks 20*lrow+2*quad: only (l,l+8)
// alias = 2-way = free). DS ops/wave-iter: 50 (v10b) -> 38.
// Per iteration it (j0 = 64*it + 32*grp):
//   [__syncthreads]  <- drains the 4 tiles K/V(2it),K/V(2it+1) (issued it-1)
//   grp0 waves issue K-tiles(it+1); grp1 waves issue V-tiles(it+1)
//   QK swapped: S^T(32x32) -> sigmoid+pack f16x4 -> 4 b64 Pw writes
//   (no barrier: same-wave in-order DS) -> 2 b128 A-frag reads -> x32 PV
// LDS: K 4x16KB + V 4x16KB + Pw 8x2560B = 151552 B (1 block/CU, 8 waves).
// ---------------------------------------------------------------------------
__global__ __launch_bounds__(512, 2) void fused_attn(const f16* __restrict__ Qb,
                                                     const f16* __restrict__ Kb,
                                                     const f16* __restrict__ Vt,
                                                     f16* __restrict__ WV) {
    __shared__ f16 smem[75776];   // K slots 4x8192 | V slots 4x8192 | Pw 8x1280
    const int t = threadIdx.x, lane = t & 63, w = t >> 6;   // w 0..7
    const int grp = w >> 2, wl = w & 3;
    const int lrow = lane & 15, quad = lane >> 4;
    f16* Pw = smem + 65536 + w * 1280;           // wave-private 32 x 40
    // XCD swizzle: 4 consecutive heads per XCD -> Q/K/V L2-resident per XCD.
    const int n = blockIdx.x;                    // 0..255
    const int xcd = n & 7, rest = n >> 3;        // rest 0..31
    const int bh = xcd * 4 + (rest & 3);
    const int strip = rest >> 2;                 // 0..7
    const int m0 = strip * 128;
    const int bb = bh >> 3, h = bh & 7;
    const f16* Qg = Qb + (size_t)bh * SQ * FQ;   // (s,f)
    const f16* Kg = Kb + (size_t)bh * SQ * FQ;   // (s,f)
    const f16* Vg = Vt + (size_t)bh * FQ * SQ;   // (f,s)

    // Q rows [m0+32*wl, +32) as MFMA fragments in registers (64 VGPR).
    // Used as the B-operand of the swapped QK (frag lane-map identical).
    f16x8 qf[2][8];
#pragma unroll
    for (int mi = 0; mi < 2; ++mi)
#pragma unroll
        for (int ks = 0; ks < 8; ++ks)
            qf[mi][ks] = *(const f16x8*)(Qg + (size_t)(m0 + 32 * wl + 16 * mi + lrow) * FQ
                                             + ks * 32 + quad * 8);

    // K staging geometry: per tile 16 insts, 2 rows x 32 granules each.
    // KB[r][p] holds source granule p^(r&7); read logical g at p = g^(r&7).
    const int krs = lane >> 5;                   // 0..1
    const int kgp = lane & 31;
    // V staging geometry: per tile 16 insts, 16 rows x 4 granules each.
    // VB[f][p] holds source granule p^((f>>1)&3); read at p = g^((f>>1)&3).
    const int vrs = lane >> 2;                   // 0..15
    const int vgp = lane & 3;

    // Prologue: stage tiles {0,1} of K and V into parity-0 slots.
    // grp0 waves stage K (2 tiles x 4 insts), grp1 waves stage V.
    if (grp == 0) {
#pragma unroll
        for (int kt = 0; kt < 2; ++kt)
#pragma unroll
            for (int i = 0; i < 4; ++i) {
                int rI = wl + i * 4;
                int r = rI * 2 + krs;
                GLOAD_LDS16(Kg + (size_t)(kt * 32 + r) * FQ + ((kgp ^ (r & 7)) << 3),
                            smem + kt * 8192 + rI * 512);
            }
    } else {
#pragma unroll
        for (int kt = 0; kt < 2; ++kt)
#pragma unroll
            for (int i = 0; i < 4; ++i) {
                int rI = wl + i * 4;
                int f = rI * 16 + vrs;
                GLOAD_LDS16(Vg + (size_t)f * SQ + kt * 32 + ((vgp ^ ((f >> 1) & 3)) << 3),
                            smem + 32768 + kt * 8192 + rI * 512);
            }
    }

    f32x4 acc_o[2][16] = {};   // rows m0+32wl+16mi+4quad+rr, f = 16nj+lrow

    for (int it = 0; it < 16; ++it) {
        const int p = it & 1;
        f16* KBc = smem + (p * 2 + grp) * 8192;
        f16* VBc = smem + 32768 + (p * 2 + grp) * 8192;
        __syncthreads();                 // drains tiles for iter it (issued it-1)
        // ---- issue K/V tiles {2(it+1), 2(it+1)+1} into the other parity ----
        if (it < 15) {
            const int pn = p ^ 1;
            const int base = (it + 1) * 64;
            if (grp == 0) {
#pragma unroll
                for (int kt = 0; kt < 2; ++kt)
#pragma unroll
                    for (int i = 0; i < 4; ++i) {
                        int rI = wl + i * 4;
                        int r = rI * 2 + krs;
                        GLOAD_LDS16(Kg + (size_t)(base + kt * 32 + r) * FQ + ((kgp ^ (r & 7)) << 3),
                                    smem + (pn * 2 + kt) * 8192 + rI * 512);
                    }
            } else {
#pragma unroll
                for (int kt = 0; kt < 2; ++kt)
#pragma unroll
                    for (int i = 0; i < 4; ++i) {
                        int rI = wl + i * 4;
                        int f = rI * 16 + vrs;
                        GLOAD_LDS16(Vg + (size_t)f * SQ + base + kt * 32 + ((vgp ^ ((f >> 1) & 3)) << 3),
                                    smem + 32768 + (pn * 2 + kt) * 8192 + rI * 512);
                    }
            }
        }
        // ---- QK^T SWAPPED: acc_s[nj][mi] = S^T; j = 16nj+4quad+rr, q = 16mi+lrow ----
        f32x4 acc_s[2][2] = {};
#pragma unroll
        for (int ks = 0; ks < 8; ++ks) {
            f16x8 bf[2];
#pragma unroll
            for (int nj = 0; nj < 2; ++nj) {
                int rk = 16 * nj + lrow;
                bf[nj] = *(const f16x8*)&KBc[rk * 256 + (((ks * 4 + quad) ^ (rk & 7)) << 3)];
            }
#pragma unroll
            for (int nj = 0; nj < 2; ++nj)
#pragma unroll
                for (int mi = 0; mi < 2; ++mi)
                    acc_s[nj][mi] = __builtin_amdgcn_mfma_f32_16x16x32_f16(
                        bf[nj], qf[mi][ks], acc_s[nj][mi], 0, 0, 0);
        }
        // ---- sigmoid + pack f16x4 -> 4 vector Pw writes (b64), wave-private ----
        // Lane's values: P[q=16mi+lrow][j=16nj+4quad+rr] -> Pw[q*40 + j].
#pragma unroll
        for (int nj = 0; nj < 2; ++nj)
#pragma unroll
            for (int mi = 0; mi < 2; ++mi) {
                f16x4 v;
#pragma unroll
                for (int rr = 0; rr < 4; ++rr)
                    v[rr] = (f16)SIG16(acc_s[nj][mi][rr]);
                *(f16x4*)&Pw[(16 * mi + lrow) * 40 + 16 * nj + 4 * quad] = v;
            }
        // ---- P as x32 A-frags (b128, same-wave in-order DS, no barrier) ----
        f16x8 ap[2];
#pragma unroll
        for (int mi = 0; mi < 2; ++mi)
            ap[mi] = *(const f16x8*)&Pw[(16 * mi + lrow) * 40 + quad * 8];
        // ---- PV: WV(32x256) += P(32x32) @ V^T, x32 MFMA, b128 V reads ----
        __builtin_amdgcn_s_setprio(1);
#pragma unroll
        for (int nj = 0; nj < 16; ++nj) {
            int f = 16 * nj + lrow;
            f16x8 bv = *(const f16x8*)&VBc[f * 32 + ((quad ^ ((f >> 1) & 3)) << 3)];
#pragma unroll
            for (int mi = 0; mi < 2; ++mi)
                acc_o[mi][nj] = __builtin_amdgcn_mfma_f32_16x16x32_f16(
                    ap[mi], bv, acc_o[mi][nj], 0, 0, 0);
        }
        __builtin_amdgcn_s_setprio(0);
    }
    // ---- combine the two j-half partials (f32, exact), TWO passes over mi ----
    // Per pass: Fb = 64 chunks x 256 f32 = 64 KB at byte 69632 (in-bounds:
    // ends 135168 <= 151552); Es f16 [0, 67584) -- disjoint. Pw dead here.
    __syncthreads();                             // all compute reads of smem done
    float* Fb = (float*)(smem + 34816);
    f16* Es = smem;                              // 128 x 264 f16
#pragma unroll
    for (int mi = 0; mi < 2; ++mi) {
        if (grp == 1) {
#pragma unroll
            for (int nj = 0; nj < 16; ++nj)
                *(f32x4*)&Fb[((wl * 16 + nj) << 8) + lane * 4] = acc_o[mi][nj];
        }
        __syncthreads();
        if (grp == 0) {
#pragma unroll
            for (int nj = 0; nj < 16; ++nj) {
                f32x4 s = acc_o[mi][nj] +
                          *(const f32x4*)&Fb[((wl * 16 + nj) << 8) + lane * 4];
#pragma unroll
                for (int rr = 0; rr < 4; ++rr)
                    Es[(32 * wl + 16 * mi + 4 * quad + rr) * 264 + 16 * nj + lrow] =
                        (f16)s[rr];
            }
        }
        __syncthreads();                 // Fb reads done before mi=1 overwrite;
    }                                    // also orders Es for the global write
#pragma unroll
    for (int it = 0; it < 8; ++it) {
        int c = it * 512 + t;
        int r = c >> 5, ck = c & 31;
        f16x8 v = *(const f16x8*)&Es[r * 264 + ck * 8];
        *(f16x8*)(WV + (size_t)(bb * SQ + m0 + r) * FH + h * 256 + ck * 8) = v;
    }
}

// ---------------------------------------------------------------------------
// out projection, split-K x4 over k = h*256+f (was x8: halves fp32-partial
// HBM traffic 32->16 MB each way). 128x128 tiles, K=512/block, grid (2,32,4)
// = 256 blocks = 1/CU. Partials ALIASED onto dead qbuf/kbuf workspace.
// ---------------------------------------------------------------------------
__global__ __launch_bounds__(256) void out_mfma4(const f16* __restrict__ WVm,
                                                 const f16* __restrict__ WoT,
                                                 float* __restrict__ PP) {
    __shared__ f16 smem[16384];
    f16* As = smem;
    f16* Bs = smem + 8192;
    f32x4 acc[4][4] = {};
    const int row0 = blockIdx.y * 128, col0 = blockIdx.x * 128;
    const int kbeg = blockIdx.z * 512;
    gemm128_sw(WVm, FH, WoT, FH, kbeg, kbeg + 512, As, Bs, acc, row0, col0);

    float* P = PP + (size_t)blockIdx.z * SQ * 4 * FQ;
    const int lane = threadIdx.x & 63, w = threadIdx.x >> 6;
    const int wr = w >> 1, wc = w & 1;
    const int lrow = lane & 15, quad = lane >> 4;
#pragma unroll
    for (int i = 0; i < 4; ++i)
#pragma unroll
        for (int rr = 0; rr < 4; ++rr) {
            int gr = row0 + wr * 64 + i * 16 + quad * 4 + rr;
#pragma unroll
            for (int j = 0; j < 4; ++j) {
                int gc = col0 + wc * 64 + j * 16 + lrow;
                P[(size_t)gr * FQ + gc] = acc[i][j][rr];
            }
        }
}

__global__ __launch_bounds__(256) void reduce_relu4(const float* __restrict__ PP,
                                                    float* __restrict__ O) {
    int idx = (blockIdx.x * 256 + threadIdx.x) * 4;
    f32x4 s = *(const f32x4*)(PP + idx);
#pragma unroll
    for (int z = 1; z < 4; ++z)
        s += *(const f32x4*)(PP + (size_t)z * 1048576 + idx);
    f32x4 r = {fmaxf(s.x, 0.f), fmaxf(s.y, 0.f), fmaxf(s.z, 0.f), fmaxf(s.w, 0.f)};
    *(f32x4*)(O + idx) = r;
}

// ---------------------------------------------------------------------------
extern "C" void kernel_launch(void* const* d_in, const int* in_sizes, int n_in,
                              void* d_out, int out_size, void* d_ws, size_t ws_size,
                              hipStream_t stream) {
    const float* x  = (const float*)d_in[0];
    const float* Wq = (const float*)d_in[1];
    const float* Wk = (const float*)d_in[2];
    const float* Wv = (const float*)d_in[3];
    const float* Wo = (const float*)d_in[4];
    float* out = (float*)d_out;

    f16* ws = (f16*)d_ws;
    f16* xh    = ws;                       // 1,048,576
    f16* wqT   = xh    + 1048576;          // 524,288
    f16* wkT   = wqT   + 524288;
    f16* wvT   = wkT   + 524288;
    f16* woT   = wvT   + 524288;           // 524,288 (k permuted to h*256+f)
    f16* qbuf  = woT   + 524288;           // 8,388,608 (b,h,s,f)
    f16* kbuf  = qbuf  + 8388608;          // (b,h,s,f)
    f16* vbuf  = kbuf  + 8388608;          // (b,h,f,s)
    f16* wvbuf = vbuf  + 8388608;          // (b*s, h*256+f)
    // pp ALIASES qbuf+kbuf (dead after fused_attn): 4 x 1,048,576 fp32 = 16 MB.
    float* pp  = (float*)qbuf;

    dim3 blk(256);
    prep_kernel<<<dim3(64, 8, 5), blk, 0, stream>>>(x, Wq, Wk, Wv, Wo,
                                                    xh, wqT, wkT, wvT, woT);

    proj_mfma<<<dim3(16, 32, 3), blk, 0, stream>>>(xh, wqT, wkT, wvT, qbuf, kbuf, vbuf);

    fused_attn<<<dim3(256), dim3(512), 0, stream>>>(qbuf, kbuf, vbuf, wvbuf);

    out_mfma4<<<dim3(2, 32, 4), blk, 0, stream>>>(wvbuf, woT, pp);
    reduce_relu4<<<dim3(1024), blk, 0, stream>>>(pp, out);
}